// Round 1
// 516.309 us; speedup vs baseline: 1.1850x; 1.1850x over previous
//
#include <hip/hip_runtime.h>

// Problem is fixed-shape: B=8192, N=4096, M=4096, G=512, CB=256.
#define B_DIM 8192
#define N_DIM 4096
#define M_DIM 4096
#define G_DIM 512

typedef short bf16x8 __attribute__((ext_vector_type(8)));
typedef float f32x4 __attribute__((ext_vector_type(4)));

typedef __attribute__((address_space(1))) const void gvoid_t;
typedef __attribute__((address_space(3))) void lvoid_t;

__device__ __forceinline__ void load_lds16(const void* g, void* l) {
    __builtin_amdgcn_global_load_lds((gvoid_t*)g, (lvoid_t*)l, 16, 0, 0);
}

// Generic->LDS addrspace cast; as3 pointers are 32-bit LDS byte offsets.
__device__ __forceinline__ unsigned lds_u32(const void* p) {
    return (unsigned)(unsigned long long)(lvoid_t*)p;
}

__device__ __forceinline__ unsigned short f2bf(float f) {
    union { float f; unsigned int u; } v; v.f = f;
    unsigned int u = v.u;
    unsigned int r = (u + 0x7fffu + ((u >> 16) & 1u)) >> 16;
    return (unsigned short)r;
}
__device__ __forceinline__ float bf2f(unsigned short s) {
    union { unsigned int u; float f; } v; v.u = ((unsigned int)s) << 16;
    return v.f;
}

// In-register H16 (unnormalized Hadamard over 16 values).
__device__ __forceinline__ void h16(float* v) {
#pragma unroll
    for (int h = 1; h < 16; h <<= 1) {
#pragma unroll
        for (int i = 0; i < 16; i++) {
            if (!(i & h)) {
                float a = v[i], b = v[i | h];
                v[i] = a + b;
                v[i | h] = a - b;
            }
        }
    }
}

// In-register H64 (unnormalized Hadamard over 64 values).
__device__ __forceinline__ void h64(float* v) {
#pragma unroll
    for (int h = 1; h < 64; h <<= 1) {
#pragma unroll
        for (int i = 0; i < 64; i++) {
            if (!(i & h)) {
                float a = v[i], b = v[i | h];
                v[i] = a + b;
                v[i | h] = a - b;
            }
        }
    }
}

// ---------------------------------------------------------------------------
// Kernel 1: W[m][g*8+j] = (cb1[q1[m][g]][j] + cb2[q2[m][g]][j]*irs) * Wscale
// Output bf16 (internal GEMM operand only).
// ---------------------------------------------------------------------------
__global__ __launch_bounds__(256) void k_build_w(
    const int* __restrict__ q1, const int* __restrict__ q2,
    const float* __restrict__ cb1, const float* __restrict__ cb2,
    const float* __restrict__ wsp, const float* __restrict__ irsp,
    unsigned short* __restrict__ W) {
    __shared__ float c1[256 * 9];
    __shared__ float c2[256 * 9];
    int t = threadIdx.x;
#pragma unroll
    for (int j = 0; j < 8; j++) {
        c1[t * 9 + j] = cb1[t * 8 + j];
        c2[t * 9 + j] = cb2[t * 8 + j];
    }
    __syncthreads();
    float ws = wsp[0];
    float irs = irsp[0] * ws;
    int gid = blockIdx.x * 256 + t;  // exact multiple, no guard needed
    int i1 = q1[gid] * 9;
    int i2 = q2[gid] * 9;
    union { unsigned short s[8]; int4 v; } o;
#pragma unroll
    for (int j = 0; j < 8; j++) {
        o.s[j] = f2bf(c1[i1 + j] * ws + c2[i2 + j] * irs);
    }
    *(int4*)(W + (size_t)gid * 8) = o.v;
}

// ---------------------------------------------------------------------------
// Kernel 1b: column-direction Hadamard on W (in place, bf16).
// ---------------------------------------------------------------------------
__global__ __launch_bounds__(256) void k_hadw(
    unsigned short* __restrict__ W, int base_mul, int step, float scale) {
    int c = blockIdx.x * 256 + threadIdx.x;
    int base = blockIdx.y * base_mul;
    float v[64];
#pragma unroll
    for (int j = 0; j < 64; j++)
        v[j] = bf2f(W[(size_t)(base + j * step) * N_DIM + c]);
    h64(v);
#pragma unroll
    for (int j = 0; j < 64; j++)
        W[(size_t)(base + j * step) * N_DIM + c] = f2bf(v[j] * scale);
}

// ---------------------------------------------------------------------------
// Kernel 2: x_rht = fht(x * SV) -> bf16 (internal GEMM operand).
// ---------------------------------------------------------------------------
__global__ __launch_bounds__(256) void k_rht_in(
    const float* __restrict__ x, const float* __restrict__ SV,
    unsigned short* __restrict__ out) {
    __shared__ float lds[4352];  // f(n) = n + (n>>4), max 4350
    int row = blockIdx.x;
    int t = threadIdx.x;
    const float* xr = x + (size_t)row * N_DIM;
    float v[16];
    // phase A: n = t + 256r
#pragma unroll
    for (int r = 0; r < 16; r++) {
        int n = t + (r << 8);
        v[r] = xr[n] * SV[n] * 0.015625f;
    }
    h16(v);
#pragma unroll
    for (int r = 0; r < 16; r++) { int n = t + (r << 8); lds[n + (n >> 4)] = v[r]; }
    __syncthreads();
    // phase B: n = 16t + r
#pragma unroll
    for (int r = 0; r < 16; r++) { int n = (t << 4) + r; v[r] = lds[n + (n >> 4)]; }
    h16(v);
#pragma unroll
    for (int r = 0; r < 16; r++) { int n = (t << 4) + r; lds[n + (n >> 4)] = v[r]; }
    __syncthreads();
    // phase C: n = (t&15) | (r<<4) | ((t>>4)<<8)
#pragma unroll
    for (int r = 0; r < 16; r++) {
        int n = (t & 15) | (r << 4) | ((t >> 4) << 8);
        v[r] = lds[n + (n >> 4)];
    }
    h16(v);
#pragma unroll
    for (int r = 0; r < 16; r++) {
        int n = (t & 15) | (r << 4) | ((t >> 4) << 8);
        lds[n + (n >> 4)] = v[r];
    }
    __syncthreads();
    unsigned short* orow = out + (size_t)row * N_DIM;
#pragma unroll
    for (int r = 0; r < 16; r++) {
        int n = t + (r << 8);
        orow[n] = f2bf(lds[n + (n >> 4)]);
    }
}

// ---------------------------------------------------------------------------
// Kernel 3: y[b,m] = SU[m] * dot(x_rht[b,:], W''[m,:])   (NT GEMM)
//
// 256x256x(BK=32) tile, 8 waves (2Mx4N), per-wave 128x64 output,
// 16x16x32 bf16 MFMA, acc[8][4].
//
// Pipeline (T3+T4): ring of 4 one-K-tile LDS buffers (4 x 32KiB = 128KiB).
// Per K-tile iteration:
//     s_waitcnt vmcnt(8)        // own tile-k loads landed (4 loads/tile,
//                               //  2 tiles allowed in flight) -- never 0
//     s_barrier                 // => ALL waves' tile-k loads landed
//     stage(k+3) -> buf[(k+3)&3]  // == buf[(k-1)&3]; tile k-1's reads all
//                               //    completed before any wave hit this
//                               //    barrier (lgkmcnt(0) precedes it)
//     ds_read 12 frags (asm, swizzled) ; lgkmcnt(0) ; sched_barrier(0)
//     setprio(1) ; 32 MFMA ; setprio(0)
// Tail iterations issue clamped dummy stages so vmcnt stays uniform.
//
// LDS swizzle (T2, rule 21: linear gload_lds dest + inverse-swz SOURCE +
// swz on READ): slot = (r<<6 | c<<4) ^ (((r>>1)&7)<<4). Staging source
// permutation reduces to lx = l ^ (l>>3); reads land 2 lanes per 16B
// bank-group (2-way = free) instead of 8-way.
//
// XCD swizzle (T1): 512 blocks, each XCD gets 2 bn-columns x 32 bm
// => per-XCD B-panel = 4MB, L2-resident.
// ---------------------------------------------------------------------------
#define DSR(D, A, OFF) \
    asm volatile("ds_read_b128 %0, %1 offset:" #OFF : "=v"(D) : "v"(A))

__global__ __launch_bounds__(512, 2) void k_gemm(
    const unsigned short* __restrict__ A,   // (B_DIM, N_DIM) bf16
    const unsigned short* __restrict__ Bw,  // (M_DIM, N_DIM) bf16  (= W'')
    const float* __restrict__ SU,
    float* __restrict__ C) {                // (B_DIM, M_DIM) f32
    __shared__ __align__(16) unsigned short lds[4 * 16384];  // 128 KiB

    int t = threadIdx.x;
    int w = t >> 6;   // wave 0..7
    int l = t & 63;

    // XCD-aware tile mapping (bijective, 512 % 8 == 0).
    int lin = blockIdx.x;
    int xcd = lin & 7;
    int idx = lin >> 3;           // 0..63
    int bn = xcd * 2 + (idx >> 5);  // 0..15  (M tiles)
    int bm = idx & 31;              // 0..31  (B tiles)

    // ---- staging: lane l writes LDS slot (row w*16 + l>>2, chunk l&3) of a
    // 128-row half; inverse-swizzled global source uses lx = l ^ (l>>3).
    int lx = l ^ (l >> 3);
    const unsigned short* aS0 =
        A + (size_t)(bm * 256 + w * 16 + (lx >> 2)) * N_DIM + (lx & 3) * 8;
    const unsigned short* aS1 = aS0 + (size_t)128 * N_DIM;
    const unsigned short* bS0 =
        Bw + (size_t)(bn * 256 + w * 16 + (lx >> 2)) * N_DIM + (lx & 3) * 8;
    const unsigned short* bS1 = bS0 + (size_t)128 * N_DIM;

    // ---- fragment read addresses (swizzled) ----
    int wm = w >> 2;   // 0..1  (M half)
    int wn = w & 3;    // 0..3  (N quarter)
    int quad = l >> 4;
    int ln = l & 15;
    unsigned ldsU = lds_u32(lds);
    unsigned aBase = ldsU +
        (unsigned)(((((wm * 128) + ln) << 6) | (quad << 4)) ^ ((ln >> 1) << 4));
    unsigned bBase = ldsU + 16384u +
        (unsigned)(((((wn * 64) + ln) << 6) | (quad << 4)) ^ ((ln >> 1) << 4));

    f32x4 acc[8][4];
#pragma unroll
    for (int i = 0; i < 8; i++)
#pragma unroll
        for (int j = 0; j < 4; j++) {
            f32x4 z = {0.f, 0.f, 0.f, 0.f};
            acc[i][j] = z;
        }

    // Stage one K-tile into ring slot (kt&3). Source clamped for tail dummies.
#define STAGE(KT) do {                                              \
        int kt_ = (KT);                                             \
        int ks_ = kt_ < 127 ? kt_ : 127;                            \
        unsigned short* d_ = lds + ((unsigned)kt_ & 3u) * 16384 + w * 512; \
        const unsigned short* sa0_ = aS0 + ks_ * 32;                \
        const unsigned short* sa1_ = aS1 + ks_ * 32;                \
        const unsigned short* sb0_ = bS0 + ks_ * 32;                \
        const unsigned short* sb1_ = bS1 + ks_ * 32;                \
        load_lds16(sa0_, d_);                                       \
        load_lds16(sa1_, d_ + 4096);                                \
        load_lds16(sb0_, d_ + 8192);                                \
        load_lds16(sb1_, d_ + 12288);                               \
    } while (0)

    STAGE(0);
    STAGE(1);
    STAGE(2);

    for (int k = 0; k < N_DIM / 32; k++) {
        asm volatile("s_waitcnt vmcnt(8)");
        __builtin_amdgcn_s_barrier();
        STAGE(k + 3);

        unsigned au = aBase + (unsigned)(k & 3) * 32768u;
        unsigned bu = bBase + (unsigned)(k & 3) * 32768u;
        bf16x8 af[8], bfr[4];
        DSR(af[0], au, 0);
        DSR(af[1], au, 1024);
        DSR(af[2], au, 2048);
        DSR(af[3], au, 3072);
        DSR(af[4], au, 4096);
        DSR(af[5], au, 5120);
        DSR(af[6], au, 6144);
        DSR(af[7], au, 7168);
        DSR(bfr[0], bu, 0);
        DSR(bfr[1], bu, 1024);
        DSR(bfr[2], bu, 2048);
        DSR(bfr[3], bu, 3072);
        asm volatile("s_waitcnt lgkmcnt(0)");
        __builtin_amdgcn_sched_barrier(0);  // rule 18: keep MFMAs below wait

        __builtin_amdgcn_s_setprio(1);
#pragma unroll
        for (int i = 0; i < 8; i++)
#pragma unroll
            for (int j = 0; j < 4; j++)
                acc[i][j] = __builtin_amdgcn_mfma_f32_16x16x32_bf16(
                    af[i], bfr[j], acc[i][j], 0, 0, 0);
        __builtin_amdgcn_s_setprio(0);
    }
    asm volatile("s_waitcnt vmcnt(0)");  // drain dummy stages before endpgm

    // epilogue: C/D layout col=lane&15, row=quad*4+reg (m89/m91-verified)
#pragma unroll
    for (int j = 0; j < 4; j++) {
        int col = bn * 256 + wn * 64 + j * 16 + ln;
        float su = SU[col];
#pragma unroll
        for (int i = 0; i < 8; i++) {
#pragma unroll
            for (int r = 0; r < 4; r++) {
                int rowg = bm * 256 + wm * 128 + i * 16 + quad * 4 + r;
                C[(size_t)rowg * M_DIM + col] = acc[i][j][r] * su;
            }
        }
    }
#undef STAGE
}

extern "C" void kernel_launch(void* const* d_in, const int* in_sizes, int n_in,
                              void* d_out, int out_size, void* d_ws, size_t ws_size,
                              hipStream_t stream) {
    const float* x    = (const float*)d_in[0];
    const int*   q1   = (const int*)d_in[1];
    const int*   q2   = (const int*)d_in[2];
    const float* SU   = (const float*)d_in[3];
    const float* SV   = (const float*)d_in[4];
    const float* cb1  = (const float*)d_in[5];
    const float* cb2  = (const float*)d_in[6];
    const float* wsp  = (const float*)d_in[7];
    const float* irsp = (const float*)d_in[8];
    float* out = (float*)d_out;  // reference output dtype: float32

    // workspace: x_rht bf16 (64MiB) | W bf16 (32MiB)  => 96MiB total
    unsigned short* xrht = (unsigned short*)d_ws;
    unsigned short* Wb   = xrht + (size_t)B_DIM * N_DIM;

    k_build_w<<<dim3((M_DIM * G_DIM) / 256), dim3(256), 0, stream>>>(
        q1, q2, cb1, cb2, wsp, irsp, Wb);
    // W'' = (1/64) H_4096 W  (column-direction Hadamard, two H64 passes)
    k_hadw<<<dim3(N_DIM / 256, 64), dim3(256), 0, stream>>>(Wb, 1, 64, 1.0f);
    k_hadw<<<dim3(N_DIM / 256, 64), dim3(256), 0, stream>>>(Wb, 64, 1, 0.015625f);
    k_rht_in<<<dim3(B_DIM), dim3(256), 0, stream>>>(x, SV, xrht);
    k_gemm<<<dim3(512), dim3(512), 0, stream>>>(xrht, Wb, SU, out);
}